// Round 2
// baseline (123.299 us; speedup 1.0000x reference)
//
#include <hip/hip_runtime.h>

// ROI bilinear pooling: img (1,200,200,512) fp32, rois (1,300,4) int32 [x,y,w,h]
// out (1,300,7,7,512) fp32.
//
// v3: one block per (roi, py). 128 threads x float4 = 512 channels.
//   - rois s_load + full y-side chain amortized over all 7 px positions
//   - 28 independent dwordx4 loads issued before first use (deep MLP)
//   - 2100 blocks (was 8400): 4x fewer dependent-chain setups
//   - all unrolled arrays statically indexed -> registers, no scratch

#define IMG_W 200
#define NCH   512
#define POOL  7
#define V4PP  (NCH / 4)   // 128 float4 per pixel

__global__ __launch_bounds__(128) void roi_bilinear_kernel(
    const float* __restrict__ img,
    const int*   __restrict__ rois,
    float*       __restrict__ out)
{
    int bid = blockIdx.x;            // r*7 + py
    int r   = bid / POOL;
    int py  = bid - r * POOL;

    int4 rv = *(const int4*)(rois + 4 * r);   // wave-uniform -> scalar load
    int x0 = rv.x, y0 = rv.y, w = rv.z, h = rv.w;

    // Strict IEEE fp32, op-for-op identical to the jax reference
    // (no fma contraction): scale = h/7.0f; ys = y0 + py*scale.
    float sy = __fdiv_rn((float)h, 7.0f);
    float sx = __fdiv_rn((float)w, 7.0f);

    // y side: shared by all 7 px positions.
    float ys = __fadd_rn((float)y0, __fmul_rn((float)py, sy));
    int   ty = (int)floorf(ys);
    float fy = __fsub_rn(ys, (float)ty);
    int   by = min(ty + 1, y0 + h - 1);

    const float4* imgv = (const float4*)img;
    int t = threadIdx.x;                      // 0..127, one float4 of channels
    int rowTo = ty * IMG_W * V4PP + t;        // float4 index: top row + lane
    int rowBo = by * IMG_W * V4PP + t;        // bottom row + lane

    // x side for all 7 positions (registers after unroll).
    int   txi[POOL], bxi[POOL];
    float fx[POOL];
    #pragma unroll
    for (int px = 0; px < POOL; ++px) {
        float xs = __fadd_rn((float)x0, __fmul_rn((float)px, sx));
        int   tx = (int)floorf(xs);
        fx[px]  = __fsub_rn(xs, (float)tx);
        txi[px] = tx;
        bxi[px] = min(tx + 1, x0 + w - 1);
    }

    // Issue all 28 loads before any use: deep MLP, duplicates hit L1.
    float4 v00[POOL], v01[POOL], v10[POOL], v11[POOL];
    #pragma unroll
    for (int px = 0; px < POOL; ++px) {
        v00[px] = imgv[rowTo + txi[px] * V4PP];
        v01[px] = imgv[rowTo + bxi[px] * V4PP];
        v10[px] = imgv[rowBo + txi[px] * V4PP];
        v11[px] = imgv[rowBo + bxi[px] * V4PP];
    }

    float gy = 1.0f - fy;
    float4* outv   = (float4*)out;
    int     outIdx = (r * 49 + py * POOL) * V4PP + t;

    #pragma unroll
    for (int px = 0; px < POOL; ++px) {
        float f = fx[px];
        float g = 1.0f - f;
        float4 o;
        o.x = gy * (g * v00[px].x + f * v01[px].x) + fy * (g * v10[px].x + f * v11[px].x);
        o.y = gy * (g * v00[px].y + f * v01[px].y) + fy * (g * v10[px].y + f * v11[px].y);
        o.z = gy * (g * v00[px].z + f * v01[px].z) + fy * (g * v10[px].z + f * v11[px].z);
        o.w = gy * (g * v00[px].w + f * v01[px].w) + fy * (g * v10[px].w + f * v11[px].w);
        outv[outIdx + px * V4PP] = o;
    }
}

extern "C" void kernel_launch(void* const* d_in, const int* in_sizes, int n_in,
                              void* d_out, int out_size, void* d_ws, size_t ws_size,
                              hipStream_t stream)
{
    const float* img  = (const float*)d_in[0];   // 1*200*200*512 fp32
    const int*   rois = (const int*)d_in[1];     // 1*300*4 int32
    float*       out  = (float*)d_out;           // 1*300*7*7*512 fp32

    const int nroi = in_sizes[1] / 4;            // 300
    dim3 grid(nroi * POOL);                      // 2100 blocks
    dim3 block(128);
    roi_bilinear_kernel<<<grid, block, 0, stream>>>(img, rois, out);
}